// Round 13
// baseline (184.055 us; speedup 1.0000x reference)
//
#include <hip/hip_runtime.h>
#include <math.h>

#define NB   64
#define D    256
#define HW   25
#define TRI  32896         // 256*257/2
#define TS   64            // tile size (i and j)
#define PSTR 68            // padded p-row stride of transposed LDS (floats)
#define REP  12            // measurement: repeat hot section inside ONE dispatch
#define EWS_OFF (1 << 20)  // e-buffer offset in d_ws (bytes); rsp in first 256 KB

// tile id t (0..9) -> band pair (bi<=bj) of 4 bands
__device__ __forceinline__ void tile_bands(int t, int& bi, int& bj) {
    bi = (t < 4) ? 0 : (t < 7) ? 1 : (t < 9) ? 2 : 3;
    const int o4 = (bi == 0) ? 0 : (bi == 1) ? 4 : (bi == 2) ? 7 : 9;
    bj = bi + (t - o4);
}

// ---------------------------------------------------------------------------
// K1 (measurement build): R10 geometry — 640 blocks x 512 thr, 64x64 tile,
// thread = 2x4.  Stages once, then REPx {compute e, store e->ews, reduce
// partial row sums -> rsp}.  Each rep writes identical values (idempotent).
// ---------------------------------------------------------------------------
__global__ __launch_bounds__(512) void tile_kernel(const float* __restrict__ feat,
                                                   float* __restrict__ rsp,
                                                   float* __restrict__ ews) {
    __shared__ __align__(16) float as[HW * PSTR];
    __shared__ __align__(16) float bs[HW * PSTR];
    __shared__ float red0[TS][17];   // i-partials, reduced over tx (16)
    __shared__ float red1[TS][33];   // j-partials, reduced over ty (32)

    const int tid = threadIdx.x;
    const int blk = blockIdx.x;
    const int b   = blk / 10;
    const int t   = blk - b * 10;
    int bi, bj; tile_bands(t, bi, bj);
    const int ibase = bi * TS, jbase = bj * TS;
    const bool diag = (bi == bj);

    const float* fb = feat + (size_t)b * D * HW;

    for (int idx = tid; idx < TS * HW; idx += 512) {
        int r = idx / HW;
        int p = idx - r * HW;
        as[p * PSTR + r] = fb[(ibase + r) * HW + p];
    }
    if (!diag) {
        for (int idx = tid; idx < TS * HW; idx += 512) {
            int r = idx / HW;
            int p = idx - r * HW;
            bs[p * PSTR + r] = fb[(jbase + r) * HW + p];
        }
    }
    __syncthreads();

    const float* bsp = diag ? as : bs;
    const int tx = tid & 15;
    const int ty = tid >> 4;          // 0..31

    for (int rep = 0; rep < REP; ++rep) {
        float acc[2][4] = {{0.f}};
#pragma unroll 5
        for (int p = 0; p < HW; ++p) {
            float2 av = *reinterpret_cast<const float2*>(&as[p * PSTR + ty * 2]);
            float4 bv = *reinterpret_cast<const float4*>(&bsp[p * PSTR + tx * 4]);
            float a2[2] = {av.x, av.y};
            float b4[4] = {bv.x, bv.y, bv.z, bv.w};
#pragma unroll
            for (int r = 0; r < 2; ++r)
#pragma unroll
                for (int q = 0; q < 4; ++q)
                    acc[r][q] += fabsf(a2[r] + b4[q]) - fabsf(a2[r] - b4[q]);
        }

        // raw e -> ews (identical triu addressing as before, different buffer)
        float* ob = ews + (size_t)b * TRI;
        if (diag) {
#pragma unroll
            for (int r = 0; r < 2; ++r) {
                const int i = ibase + ty * 2 + r;
                const int rowoff = (i * (513 - i)) >> 1;
#pragma unroll
                for (int q = 0; q < 4; ++q) {
                    const int j = jbase + tx * 4 + q;
                    if (j >= i) ob[rowoff + (j - i)] = acc[r][q];
                }
            }
        } else {
#pragma unroll
            for (int r = 0; r < 2; ++r) {
                const int i = ibase + ty * 2 + r;
                const int rowoff = (i * (513 - i)) >> 1;
#pragma unroll
                for (int q = 0; q < 4; ++q) {
                    const int j = jbase + tx * 4 + q;
                    ob[rowoff + (j - i)] = acc[r][q];
                }
            }
        }

        // partial row vectors
        float pi[2];
#pragma unroll
        for (int r = 0; r < 2; ++r) pi[r] = acc[r][0] + acc[r][1] + acc[r][2] + acc[r][3];
#pragma unroll
        for (int r = 0; r < 2; ++r) red0[ty * 2 + r][tx] = pi[r];
        if (!diag) {
            float pj[4];
#pragma unroll
            for (int q = 0; q < 4; ++q) pj[q] = acc[0][q] + acc[1][q];
#pragma unroll
            for (int q = 0; q < 4; ++q) red1[tx * 4 + q][ty] = pj[q];
        }
        __syncthreads();

        if (tid < TS) {
            float si = 0.f;
#pragma unroll
            for (int x = 0; x < 16; ++x) si += red0[tid][x];
            rsp[((b * 4 + bi) * 4 + (bj - bi)) * TS + tid] = si;
        } else if (tid < 2 * TS && !diag) {
            const int c = tid - TS;
            float sj = 0.f;
#pragma unroll
            for (int x = 0; x < 32; ++x) sj += red1[c][x];
            rsp[((b * 4 + bj) * 4 + (4 - bj + bi)) * TS + c] = sj;
        }
        __syncthreads();   // protect red0/red1 reuse across reps
    }
}

// ---------------------------------------------------------------------------
// K2 (measurement build): pure function out = sc*(e - (rs_i+rs_j)/256).
// Gathers rsum once, then REPx {load e from ews, write final to out}.
// ---------------------------------------------------------------------------
__global__ __launch_bounds__(512) void center_kernel(const float* __restrict__ temp,
                                                     const float* __restrict__ rsp,
                                                     const float* __restrict__ ews,
                                                     float* __restrict__ out) {
    __shared__ float rsum[2][TS];

    const int tid = threadIdx.x;
    const int blk = blockIdx.x;
    const int b   = blk / 10;
    const int t   = blk - b * 10;
    int bi, bj; tile_bands(t, bi, bj);
    const int ibase = bi * TS, jbase = bj * TS;
    const bool diag = (bi == bj);

    if (tid < TS) {
        float s = 0.f;
#pragma unroll
        for (int sl = 0; sl < 4; ++sl) s += rsp[((b * 4 + bi) * 4 + sl) * TS + tid];
        rsum[0][tid] = s;
    } else if (tid < 2 * TS) {
        const int c = tid - TS;
        float s = 0.f;
#pragma unroll
        for (int sl = 0; sl < 4; ++sl) s += rsp[((b * 4 + bj) * 4 + sl) * TS + c];
        rsum[1][c] = s;
    }
    __syncthreads();

    const int tx = tid & 15;
    const int ty = tid >> 4;
    const float sc = 0.5f * expf(temp[0]);
    const float* eb = ews + (size_t)b * TRI;
    float* ob = out + (size_t)b * TRI;

    for (int rep = 0; rep < REP; ++rep) {
#pragma unroll
        for (int r = 0; r < 2; ++r) {
            const int i = ibase + ty * 2 + r;
            const int rowoff = (i * (513 - i)) >> 1;
            const float ri = rsum[0][ty * 2 + r];
#pragma unroll
            for (int q = 0; q < 4; ++q) {
                const int j = jbase + tx * 4 + q;
                if (!diag || j >= i) {
                    const float e = eb[rowoff + (j - i)];
                    ob[rowoff + (j - i)] = sc * (e - (ri + rsum[1][tx * 4 + q]) * (1.0f / 256.0f));
                }
            }
        }
    }
}

extern "C" void kernel_launch(void* const* d_in, const int* in_sizes, int n_in,
                              void* d_out, int out_size, void* d_ws, size_t ws_size,
                              hipStream_t stream) {
    const float* feat = (const float*)d_in[0];
    const float* temp = (const float*)d_in[1];
    float* out = (float*)d_out;
    float* rsp = (float*)d_ws;                          // 256 KB slot vectors
    float* ews = (float*)((char*)d_ws + EWS_OFF);       // 8.4 MB raw e buffer

    tile_kernel<<<NB * 10, 512, 0, stream>>>(feat, rsp, ews);
    center_kernel<<<NB * 10, 512, 0, stream>>>(temp, rsp, ews, out);
}

// Round 14
// 25.771 us; speedup vs baseline: 7.1421x; 7.1421x over previous
//
#include <hip/hip_runtime.h>
#include <math.h>

#define NB   64
#define D    256
#define HW   25
#define TRI  32896         // 256*257/2
#define TS   64            // tile size (i and j)
#define PSTR 68            // padded p-row stride of transposed LDS (floats)
#define EWS_OFF (1 << 19)  // padded-e buffer at d_ws + 512 KB (rsp uses first 256 KB)

// tile id t (0..9) -> band pair (bi<=bj) of 4 bands
__device__ __forceinline__ void tile_bands(int t, int& bi, int& bj) {
    bi = (t < 4) ? 0 : (t < 7) ? 1 : (t < 9) ? 2 : 3;
    const int o4 = (bi == 0) ? 0 : (bi == 1) ? 4 : (bi == 2) ? 7 : 9;
    bj = bi + (t - o4);
}

// ---------------------------------------------------------------------------
// K1: R10 geometry (640 blocks x 512 thr, 64x64 tile, 2x4/thread).
// Changes vs R10 (from R13 counters: VALU-bound 69.5%, stores/addressing are
// the measured excess):
//  - e goes to a PADDED per-tile buffer ews[blk][64][64]: 2 aligned
//    global_store_dwordx4 per thread, no triu math in K1.
//  - dual accumulators accP/accM (independent chains, abs-modifier folding).
// Row-sum slot scheme unchanged (collision-free, no atomics).
// ---------------------------------------------------------------------------
__global__ __launch_bounds__(512) void tile_kernel(const float* __restrict__ feat,
                                                   float* __restrict__ rsp,
                                                   float* __restrict__ ews) {
    __shared__ __align__(16) float as[HW * PSTR];
    __shared__ __align__(16) float bs[HW * PSTR];
    __shared__ float red0[TS][17];   // i-partials, reduced over tx (16)
    __shared__ float red1[TS][33];   // j-partials, reduced over ty (32)

    const int tid = threadIdx.x;
    const int blk = blockIdx.x;
    const int b   = blk / 10;
    const int t   = blk - b * 10;
    int bi, bj; tile_bands(t, bi, bj);
    const bool diag = (bi == bj);

    const float* fb = feat + (size_t)b * D * HW;

    for (int idx = tid; idx < TS * HW; idx += 512) {
        int r = idx / HW;
        int p = idx - r * HW;
        as[p * PSTR + r] = fb[(bi * TS + r) * HW + p];
    }
    if (!diag) {
        for (int idx = tid; idx < TS * HW; idx += 512) {
            int r = idx / HW;
            int p = idx - r * HW;
            bs[p * PSTR + r] = fb[(bj * TS + r) * HW + p];
        }
    }
    __syncthreads();

    const float* bsp = diag ? as : bs;
    const int tx = tid & 15;
    const int ty = tid >> 4;          // 0..31

    float accP[2][4] = {{0.f}};
    float accM[2][4] = {{0.f}};
#pragma unroll 5
    for (int p = 0; p < HW; ++p) {
        float2 av = *reinterpret_cast<const float2*>(&as[p * PSTR + ty * 2]);
        float4 bv = *reinterpret_cast<const float4*>(&bsp[p * PSTR + tx * 4]);
        float a2[2] = {av.x, av.y};
        float b4[4] = {bv.x, bv.y, bv.z, bv.w};
#pragma unroll
        for (int r = 0; r < 2; ++r)
#pragma unroll
            for (int q = 0; q < 4; ++q) {
                accP[r][q] += fabsf(a2[r] + b4[q]);
                accM[r][q] += fabsf(a2[r] - b4[q]);
            }
    }
    float acc[2][4];
#pragma unroll
    for (int r = 0; r < 2; ++r)
#pragma unroll
        for (int q = 0; q < 4; ++q) acc[r][q] = accP[r][q] - accM[r][q];

    // padded e store: 2 aligned dwordx4, no triu addressing
    float* eb = ews + ((size_t)blk << 12);
#pragma unroll
    for (int r = 0; r < 2; ++r) {
        float4 v = make_float4(acc[r][0], acc[r][1], acc[r][2], acc[r][3]);
        *reinterpret_cast<float4*>(&eb[(ty * 2 + r) * TS + tx * 4]) = v;
    }

    // partial row vectors -> slots (unchanged)
    float pi[2];
#pragma unroll
    for (int r = 0; r < 2; ++r) pi[r] = acc[r][0] + acc[r][1] + acc[r][2] + acc[r][3];
#pragma unroll
    for (int r = 0; r < 2; ++r) red0[ty * 2 + r][tx] = pi[r];
    if (!diag) {
        float pj[4];
#pragma unroll
        for (int q = 0; q < 4; ++q) pj[q] = acc[0][q] + acc[1][q];
#pragma unroll
        for (int q = 0; q < 4; ++q) red1[tx * 4 + q][ty] = pj[q];
    }
    __syncthreads();

    if (tid < TS) {
        float si = 0.f;
#pragma unroll
        for (int x = 0; x < 16; ++x) si += red0[tid][x];
        rsp[((b * 4 + bi) * 4 + (bj - bi)) * TS + tid] = si;
    } else if (tid < 2 * TS && !diag) {
        const int c = tid - TS;
        float sj = 0.f;
#pragma unroll
        for (int x = 0; x < 32; ++x) sj += red1[c][x];
        rsp[((b * 4 + bj) * 4 + (4 - bj + bi)) * TS + c] = sj;
    }
}

// ---------------------------------------------------------------------------
// K2: same grid/tile map. Gather rsum from slots, load e as aligned dwordx4
// from the padded buffer, write the final centered triu value (the only
// mandatory scattered access left):
//   out = sc*(e - (rs_i+rs_j)/256),  sc = 0.5*exp(T)
// ---------------------------------------------------------------------------
__global__ __launch_bounds__(512) void center_kernel(const float* __restrict__ temp,
                                                     const float* __restrict__ rsp,
                                                     const float* __restrict__ ews,
                                                     float* __restrict__ out) {
    __shared__ float rsum[2][TS];

    const int tid = threadIdx.x;
    const int blk = blockIdx.x;
    const int b   = blk / 10;
    const int t   = blk - b * 10;
    int bi, bj; tile_bands(t, bi, bj);
    const int ibase = bi * TS, jbase = bj * TS;
    const bool diag = (bi == bj);

    if (tid < TS) {
        float s = 0.f;
#pragma unroll
        for (int sl = 0; sl < 4; ++sl) s += rsp[((b * 4 + bi) * 4 + sl) * TS + tid];
        rsum[0][tid] = s;
    } else if (tid < 2 * TS) {
        const int c = tid - TS;
        float s = 0.f;
#pragma unroll
        for (int sl = 0; sl < 4; ++sl) s += rsp[((b * 4 + bj) * 4 + sl) * TS + c];
        rsum[1][c] = s;
    }
    __syncthreads();

    const int tx = tid & 15;
    const int ty = tid >> 4;
    const float sc  = 0.5f * expf(temp[0]);
    const float inv = 1.0f / 256.0f;
    const float* eb = ews + ((size_t)blk << 12);
    float* ob = out + (size_t)b * TRI;

#pragma unroll
    for (int r = 0; r < 2; ++r) {
        const int i = ibase + ty * 2 + r;
        const int rowoff = (i * (513 - i)) >> 1;
        const float ri = rsum[0][ty * 2 + r];
        float4 ev = *reinterpret_cast<const float4*>(&eb[(ty * 2 + r) * TS + tx * 4]);
        float e4[4] = {ev.x, ev.y, ev.z, ev.w};
#pragma unroll
        for (int q = 0; q < 4; ++q) {
            const int j = jbase + tx * 4 + q;
            if (!diag || j >= i)
                ob[rowoff + (j - i)] = sc * (e4[q] - (ri + rsum[1][tx * 4 + q]) * inv);
        }
    }
}

extern "C" void kernel_launch(void* const* d_in, const int* in_sizes, int n_in,
                              void* d_out, int out_size, void* d_ws, size_t ws_size,
                              hipStream_t stream) {
    const float* feat = (const float*)d_in[0];
    const float* temp = (const float*)d_in[1];
    float* out = (float*)d_out;
    float* rsp = (float*)d_ws;                          // 256 KB slot vectors
    float* ews = (float*)((char*)d_ws + EWS_OFF);       // 10.5 MB padded e tiles

    tile_kernel<<<NB * 10, 512, 0, stream>>>(feat, rsp, ews);
    center_kernel<<<NB * 10, 512, 0, stream>>>(temp, rsp, ews, out);
}

// Round 15
// 24.403 us; speedup vs baseline: 7.5423x; 1.0560x over previous
//
#include <hip/hip_runtime.h>
#include <math.h>

#define NB   64
#define D    256
#define HW   25
#define TRI  32896         // 256*257/2
#define TS   64            // tile size (i and j)
#define PSTR 68            // padded p-row stride of transposed LDS (floats)
#define EWS_OFF (1 << 19)  // padded-e buffer at d_ws + 512 KB (rsp uses first 256 KB)

// tile id t (0..9) -> band pair (bi<=bj) of 4 bands
__device__ __forceinline__ void tile_bands(int t, int& bi, int& bj) {
    bi = (t < 4) ? 0 : (t < 7) ? 1 : (t < 9) ? 2 : 3;
    const int o4 = (bi == 0) ? 0 : (bi == 1) ? 4 : (bi == 2) ? 7 : 9;
    bj = bi + (t - o4);
}

// ---------------------------------------------------------------------------
// K1: byte-identical to the R14 winner.  640 blocks x 512 thr, 64x64 tile,
// 2x4/thread, dual accumulators, padded e-tile store (2 aligned dwordx4),
// collision-free row-sum slots.
// ---------------------------------------------------------------------------
__global__ __launch_bounds__(512) void tile_kernel(const float* __restrict__ feat,
                                                   float* __restrict__ rsp,
                                                   float* __restrict__ ews) {
    __shared__ __align__(16) float as[HW * PSTR];
    __shared__ __align__(16) float bs[HW * PSTR];
    __shared__ float red0[TS][17];   // i-partials, reduced over tx (16)
    __shared__ float red1[TS][33];   // j-partials, reduced over ty (32)

    const int tid = threadIdx.x;
    const int blk = blockIdx.x;
    const int b   = blk / 10;
    const int t   = blk - b * 10;
    int bi, bj; tile_bands(t, bi, bj);
    const bool diag = (bi == bj);

    const float* fb = feat + (size_t)b * D * HW;

    for (int idx = tid; idx < TS * HW; idx += 512) {
        int r = idx / HW;
        int p = idx - r * HW;
        as[p * PSTR + r] = fb[(bi * TS + r) * HW + p];
    }
    if (!diag) {
        for (int idx = tid; idx < TS * HW; idx += 512) {
            int r = idx / HW;
            int p = idx - r * HW;
            bs[p * PSTR + r] = fb[(bj * TS + r) * HW + p];
        }
    }
    __syncthreads();

    const float* bsp = diag ? as : bs;
    const int tx = tid & 15;
    const int ty = tid >> 4;          // 0..31

    float accP[2][4] = {{0.f}};
    float accM[2][4] = {{0.f}};
#pragma unroll 5
    for (int p = 0; p < HW; ++p) {
        float2 av = *reinterpret_cast<const float2*>(&as[p * PSTR + ty * 2]);
        float4 bv = *reinterpret_cast<const float4*>(&bsp[p * PSTR + tx * 4]);
        float a2[2] = {av.x, av.y};
        float b4[4] = {bv.x, bv.y, bv.z, bv.w};
#pragma unroll
        for (int r = 0; r < 2; ++r)
#pragma unroll
            for (int q = 0; q < 4; ++q) {
                accP[r][q] += fabsf(a2[r] + b4[q]);
                accM[r][q] += fabsf(a2[r] - b4[q]);
            }
    }
    float acc[2][4];
#pragma unroll
    for (int r = 0; r < 2; ++r)
#pragma unroll
        for (int q = 0; q < 4; ++q) acc[r][q] = accP[r][q] - accM[r][q];

    // padded e store: 2 aligned dwordx4, no triu addressing
    float* eb = ews + ((size_t)blk << 12);
#pragma unroll
    for (int r = 0; r < 2; ++r) {
        float4 v = make_float4(acc[r][0], acc[r][1], acc[r][2], acc[r][3]);
        *reinterpret_cast<float4*>(&eb[(ty * 2 + r) * TS + tx * 4]) = v;
    }

    // partial row vectors -> slots
    float pi[2];
#pragma unroll
    for (int r = 0; r < 2; ++r) pi[r] = acc[r][0] + acc[r][1] + acc[r][2] + acc[r][3];
#pragma unroll
    for (int r = 0; r < 2; ++r) red0[ty * 2 + r][tx] = pi[r];
    if (!diag) {
        float pj[4];
#pragma unroll
        for (int q = 0; q < 4; ++q) pj[q] = acc[0][q] + acc[1][q];
#pragma unroll
        for (int q = 0; q < 4; ++q) red1[tx * 4 + q][ty] = pj[q];
    }
    __syncthreads();

    if (tid < TS) {
        float si = 0.f;
#pragma unroll
        for (int x = 0; x < 16; ++x) si += red0[tid][x];
        rsp[((b * 4 + bi) * 4 + (bj - bi)) * TS + tid] = si;
    } else if (tid < 2 * TS && !diag) {
        const int c = tid - TS;
        float sj = 0.f;
#pragma unroll
        for (int x = 0; x < 32; ++x) sj += red1[c][x];
        rsp[((b * 4 + bj) * 4 + (4 - bj + bi)) * TS + c] = sj;
    }
}

// ---------------------------------------------------------------------------
// K2: coalescing remap (only change vs R14).  Thread's j-set is now
// {jbase + q*16 + tx} instead of {jbase + tx*4 + q}: per store/load
// instruction the 16 tx-lanes touch CONTIGUOUS dwords (4x64B segments per
// wave-op instead of ~16 scattered lines).  e is read from the padded buffer
// at [row][q*16+tx]; final value written once:
//   out = sc*(e - (rs_i+rs_j)/256),  sc = 0.5*exp(T)
// ---------------------------------------------------------------------------
__global__ __launch_bounds__(512) void center_kernel(const float* __restrict__ temp,
                                                     const float* __restrict__ rsp,
                                                     const float* __restrict__ ews,
                                                     float* __restrict__ out) {
    __shared__ float rsum[2][TS];

    const int tid = threadIdx.x;
    const int blk = blockIdx.x;
    const int b   = blk / 10;
    const int t   = blk - b * 10;
    int bi, bj; tile_bands(t, bi, bj);
    const int ibase = bi * TS, jbase = bj * TS;
    const bool diag = (bi == bj);

    if (tid < TS) {
        float s = 0.f;
#pragma unroll
        for (int sl = 0; sl < 4; ++sl) s += rsp[((b * 4 + bi) * 4 + sl) * TS + tid];
        rsum[0][tid] = s;
    } else if (tid < 2 * TS) {
        const int c = tid - TS;
        float s = 0.f;
#pragma unroll
        for (int sl = 0; sl < 4; ++sl) s += rsp[((b * 4 + bj) * 4 + sl) * TS + c];
        rsum[1][c] = s;
    }
    __syncthreads();

    const int tx = tid & 15;
    const int ty = tid >> 4;
    const float sc  = 0.5f * expf(temp[0]);
    const float inv = 1.0f / 256.0f;
    const float* eb = ews + ((size_t)blk << 12);
    float* ob = out + (size_t)b * TRI;

#pragma unroll
    for (int r = 0; r < 2; ++r) {
        const int i = ibase + ty * 2 + r;
        const int rowoff = (i * (513 - i)) >> 1;
        const float ri = rsum[0][ty * 2 + r];
        const int rowbase = (ty * 2 + r) * TS;
#pragma unroll
        for (int q = 0; q < 4; ++q) {
            const int jc = q * 16 + tx;            // contiguous across tx-lanes
            const int j  = jbase + jc;
            if (!diag || j >= i) {
                const float e = eb[rowbase + jc];
                ob[rowoff + (j - i)] = sc * (e - (ri + rsum[1][jc]) * inv);
            }
        }
    }
}

extern "C" void kernel_launch(void* const* d_in, const int* in_sizes, int n_in,
                              void* d_out, int out_size, void* d_ws, size_t ws_size,
                              hipStream_t stream) {
    const float* feat = (const float*)d_in[0];
    const float* temp = (const float*)d_in[1];
    float* out = (float*)d_out;
    float* rsp = (float*)d_ws;                          // 256 KB slot vectors
    float* ews = (float*)((char*)d_ws + EWS_OFF);       // 10.5 MB padded e tiles

    tile_kernel<<<NB * 10, 512, 0, stream>>>(feat, rsp, ews);
    center_kernel<<<NB * 10, 512, 0, stream>>>(temp, rsp, ews, out);
}